// Round 3
// baseline (2009.584 us; speedup 1.0000x reference)
//
#include <hip/hip_runtime.h>

#define N_TOK 32768
#define N_EMB 4096
#define DIM 256

// ---------------- ws layout ----------------
// [0, 16384)        counts    uint[4096]
// [16384, 16388)    loss_acc  float
// [16896, 33280)    e2_np     float[4096]   (numpy-pairwise fp32 row norms of w)
// [33280, 164352)   x2_np     float[32768]  (numpy-pairwise fp32 row norms of x)

// Replicates numpy pairwise_sum over 128 fp32 squares:
// r[0..7]=a[0..7]; 15x 8-wide accumulate; combine ((r0+r1)+(r2+r3))+((r4+r5)+(r6+r7)).
// contract(off): numpy materializes x**2 (rounded) then adds — no FMA allowed.
__device__ __forceinline__ float pw128_sq(const float4* a4) {
#pragma clang fp contract(off)
    float4 v0 = a4[0], v1 = a4[1];
    float r0 = v0.x * v0.x, r1 = v0.y * v0.y, r2 = v0.z * v0.z, r3 = v0.w * v0.w;
    float r4 = v1.x * v1.x, r5 = v1.y * v1.y, r6 = v1.z * v1.z, r7 = v1.w * v1.w;
    #pragma unroll
    for (int i = 1; i < 16; ++i) {
        v0 = a4[2 * i]; v1 = a4[2 * i + 1];
        float s;
        s = v0.x * v0.x; r0 += s;
        s = v0.y * v0.y; r1 += s;
        s = v0.z * v0.z; r2 += s;
        s = v0.w * v0.w; r3 += s;
        s = v1.x * v1.x; r4 += s;
        s = v1.y * v1.y; r5 += s;
        s = v1.z * v1.z; r6 += s;
        s = v1.w * v1.w; r7 += s;
    }
    return ((r0 + r1) + (r2 + r3)) + ((r4 + r5) + (r6 + r7));
}

__global__ __launch_bounds__(256) void k_norm_np(const float* __restrict__ src,
                                                 float* __restrict__ dst, int nrows) {
#pragma clang fp contract(off)
    int row = blockIdx.x * 256 + threadIdx.x;
    if (row >= nrows) return;
    const float4* a = (const float4*)(src + (size_t)row * DIM);
    float lo = pw128_sq(a);
    float hi = pw128_sq(a + 32);
    dst[row] = lo + hi;   // numpy: pw(first128) + pw(second128)
}

// ---------------- scoring GEMM + argmin (np-fp32-bucket-exact) ----------------
// fp32 GEMM ranks candidates (top-2 per thread = 32/token). Refinement replays
// the reference's fp32 ops: d = f32( f32(x2+e2) - 2*f32(dot64) ), first-index
// tie-break — matching np.argmin over the fp32-quantized distance matrix.
__global__ __launch_bounds__(256) void k_score(const float* __restrict__ x,
                                               const float* __restrict__ w,
                                               const float* __restrict__ e2_np,
                                               const float* __restrict__ x2_np,
                                               float* __restrict__ out_idx,
                                               unsigned int* __restrict__ counts) {
    __shared__ float As[64 * 64];
    __shared__ float Bs[64 * 64];
    __shared__ float red_v[64 * 4];
    __shared__ int   red_i[64 * 4];

    const int t  = threadIdx.x;
    const int tx = t & 15;        // code column group
    const int ty = t >> 4;        // token row group
    const int tok0 = blockIdx.x * 64;

    const int lr = t >> 4;        // staging row base (0..15)
    const int lc = t & 15;        // staging col granule (0..15)

    float v0[4] = {3.4e38f, 3.4e38f, 3.4e38f, 3.4e38f};
    float v1[4] = {3.4e38f, 3.4e38f, 3.4e38f, 3.4e38f};
    int   i0[4] = {0, 0, 0, 0};
    int   i1[4] = {0, 0, 0, 0};

    for (int jt = 0; jt < N_EMB; jt += 64) {
        float acc[4][4] = {};
        for (int dc = 0; dc < DIM; dc += 64) {
            __syncthreads();  // protect LDS from previous chunk's readers
            #pragma unroll
            for (int p = 0; p < 4; ++p) {
                int r = lr + 16 * p;
                float4 va = *(const float4*)(x + (size_t)(tok0 + r) * DIM + dc + lc * 4);
                *(float4*)(As + r * 64 + ((lc ^ (r & 7)) << 2)) = va;
                float4 vb = *(const float4*)(w + (size_t)(jt + r) * DIM + dc + lc * 4);
                *(float4*)(Bs + r * 64 + ((lc ^ (r & 7)) << 2)) = vb;
            }
            __syncthreads();
            #pragma unroll
            for (int dg = 0; dg < 16; ++dg) {
                float4 a4[4], b4[4];
                #pragma unroll
                for (int i = 0; i < 4; ++i) {
                    int tr = ty + 16 * i;
                    a4[i] = *(const float4*)(As + tr * 64 + ((dg ^ (tr & 7)) << 2));
                    int cr = tx + 16 * i;
                    b4[i] = *(const float4*)(Bs + cr * 64 + ((dg ^ (cr & 7)) << 2));
                }
                #pragma unroll
                for (int i = 0; i < 4; ++i)
                    #pragma unroll
                    for (int j = 0; j < 4; ++j) {
                        acc[i][j] += a4[i].x * b4[j].x;
                        acc[i][j] += a4[i].y * b4[j].y;
                        acc[i][j] += a4[i].z * b4[j].z;
                        acc[i][j] += a4[i].w * b4[j].w;
                    }
            }
        }
        // score this 64-code tile, update running top-2
        #pragma unroll
        for (int j = 0; j < 4; ++j) {
            int code = jt + tx + 16 * j;
            float e2 = e2_np[code];
            #pragma unroll
            for (int i = 0; i < 4; ++i) {
                float s = e2 - 2.0f * acc[i][j];
                if (s < v0[i]) {
                    v1[i] = v0[i]; i1[i] = i0[i];
                    v0[i] = s;     i0[i] = code;
                } else if (s < v1[i]) {
                    v1[i] = s;     i1[i] = code;
                }
            }
        }
    }

    // ---- candidate dump: 32 candidates per token into LDS (reuse As/Bs) ----
    __syncthreads();
    float* cand_v = As;                  // [64][32]
    int*   cand_i = (int*)(As + 2048);   // [64][32]
    float* bv_s   = Bs;                  // [64]
    #pragma unroll
    for (int i = 0; i < 4; ++i) {
        int row = ty + 16 * i;
        cand_v[row * 32 + tx * 2]     = v0[i];
        cand_i[row * 32 + tx * 2]     = i0[i];
        cand_v[row * 32 + tx * 2 + 1] = v1[i];
        cand_i[row * 32 + tx * 2 + 1] = i1[i];
    }
    __syncthreads();
    if (t < 64) {
        float bv = cand_v[t * 32];
        #pragma unroll
        for (int k = 1; k < 32; ++k) bv = fminf(bv, cand_v[t * 32 + k]);
        bv_s[t] = bv;
    }
    __syncthreads();

    // ---- np-fp32-exact refinement: 4 threads per token, 8 candidates each ----
    {
#pragma clang fp contract(off)
        int token = t >> 2, slot = t & 3;
        float bv = bv_s[token];
        float x2 = x2_np[tok0 + token];
        float bd = 3.4e38f;
        int bi = 0x7fffffff;
        const float4* xr = (const float4*)(x + (size_t)(tok0 + token) * DIM);
        for (int c = slot * 8; c < slot * 8 + 8; ++c) {
            float v = cand_v[token * 32 + c];
            if (v <= bv + 1e-4f) {
                int code = cand_i[token * 32 + c];
                const float4* wr = (const float4*)(w + (size_t)code * DIM);
                double dot = 0.0;
                for (int g = 0; g < 64; ++g) {
                    float4 xv = xr[g];
                    float4 wv = wr[g];
                    dot += (double)xv.x * (double)wv.x;
                    dot += (double)xv.y * (double)wv.y;
                    dot += (double)xv.z * (double)wv.z;
                    dot += (double)xv.w * (double)wv.w;
                }
                float M  = (float)dot;          // BLAS sgemm entry (to ~2e-9)
                float t2 = 2.0f * M;            // exact
                float S  = x2 + e2_np[code];    // fp32 add (np broadcast add)
                float d  = S - t2;              // fp32 sub -> the ulp(256) bucket
                if (d < bd || (d == bd && code < bi)) { bd = d; bi = code; }
            }
        }
        red_v[token * 4 + slot] = bd;
        red_i[token * 4 + slot] = bi;
    }
    __syncthreads();
    if (t < 64) {
        float fv = red_v[t * 4];
        int   fi = red_i[t * 4];
        #pragma unroll
        for (int k = 1; k < 4; ++k) {
            float v  = red_v[t * 4 + k];
            int   i2 = red_i[t * 4 + k];
            if (v < fv || (v == fv && i2 < fi)) { fv = v; fi = i2; }
        }
        out_idx[tok0 + t] = (float)fi;
        atomicAdd(&counts[fi], 1u);
    }
}

// ---------------- gather quantized + loss ----------------
__global__ __launch_bounds__(256) void k_gather(const float* __restrict__ x,
                                                const float* __restrict__ w,
                                                const float* __restrict__ out_idx,
                                                float* __restrict__ outq,
                                                float* __restrict__ loss_acc) {
    int gid = blockIdx.x * 256 + threadIdx.x;   // float4 index, 2,097,152 total
    int token = gid >> 6;
    int d4 = gid & 63;
    int idx = (int)out_idx[token];
    float4 q  = ((const float4*)(w + (size_t)idx * DIM))[d4];
    float4 xv = ((const float4*)x)[gid];
    ((float4*)outq)[gid] = q;
    float dx = q.x - xv.x, dy = q.y - xv.y, dz = q.z - xv.z, dw = q.w - xv.w;
    float sse = dx * dx + dy * dy + dz * dz + dw * dw;
    #pragma unroll
    for (int off = 32; off > 0; off >>= 1) sse += __shfl_down(sse, off, 64);
    __shared__ float sred[4];
    int lane = threadIdx.x & 63, wv = threadIdx.x >> 6;
    if (lane == 0) sred[wv] = sse;
    __syncthreads();
    if (threadIdx.x == 0)
        atomicAdd(loss_acc, sred[0] + sred[1] + sred[2] + sred[3]);
}

// ---------------- one-hot encodings (537 MB of stores) ----------------
__global__ __launch_bounds__(256) void k_onehot(const float* __restrict__ out_idx,
                                                float* __restrict__ enc) {
    int token = blockIdx.x;
    int idx = (int)out_idx[token];
    float4* row = (float4*)(enc + (size_t)token * N_EMB);
    #pragma unroll
    for (int p = 0; p < 4; ++p) {
        int g = threadIdx.x + 256 * p;     // granule 0..1023
        float4 v = make_float4(0.f, 0.f, 0.f, 0.f);
        int d0 = g * 4;
        if (idx >= d0 && idx < d0 + 4) ((float*)&v)[idx - d0] = 1.0f;
        row[g] = v;
    }
}

// ---------------- perplexity + loss finalize ----------------
__global__ __launch_bounds__(256) void k_final(const unsigned int* __restrict__ counts,
                                               const float* __restrict__ loss_acc,
                                               float* __restrict__ out_perp,
                                               float* __restrict__ out_loss) {
    __shared__ float sred[4];
    int t = threadIdx.x;
    float h = 0.f;
    for (int k = t; k < N_EMB; k += 256) {
        float p = (float)counts[k] * (1.0f / N_TOK);
        h += p * logf(p + 1e-10f);
    }
    #pragma unroll
    for (int off = 32; off > 0; off >>= 1) h += __shfl_down(h, off, 64);
    if ((t & 63) == 0) sred[t >> 6] = h;
    __syncthreads();
    if (t == 0) {
        float s = sred[0] + sred[1] + sred[2] + sred[3];
        *out_perp = expf(-s);
        *out_loss = loss_acc[0] * 1.25f / 8388608.0f;
    }
}

extern "C" void kernel_launch(void* const* d_in, const int* in_sizes, int n_in,
                              void* d_out, int out_size, void* d_ws, size_t ws_size,
                              hipStream_t stream) {
    const float* x = (const float*)d_in[0];
    const float* w = (const float*)d_in[1];
    float* out  = (float*)d_out;
    float* out0 = out;                       // quantized_st [32768*256]
    float* out1 = out0 + 8388608;            // perplexity   [1]
    float* out2 = out1 + 1;                  // encodings    [32768*4096]
    float* out3 = out2 + 134217728;          // indices      [32768] (as float)
    float* out4 = out3 + 32768;              // loss         [1]

    unsigned int* counts = (unsigned int*)d_ws;
    float* loss_acc = (float*)((char*)d_ws + 16384);
    float* e2_np    = (float*)((char*)d_ws + 16896);
    float* x2_np    = (float*)((char*)d_ws + 33280);

    hipMemsetAsync(d_ws, 0, 16640, stream);
    k_norm_np<<<N_EMB / 256, 256, 0, stream>>>(w, e2_np, N_EMB);
    k_norm_np<<<N_TOK / 256, 256, 0, stream>>>(x, x2_np, N_TOK);
    k_score<<<N_TOK / 64, 256, 0, stream>>>(x, w, e2_np, x2_np, out3, counts);
    k_gather<<<N_TOK * 64 / 256, 256, 0, stream>>>(x, w, out3, out0, loss_acc);
    k_onehot<<<N_TOK, 256, 0, stream>>>(out3, out2);
    k_final<<<1, 256, 0, stream>>>(counts, loss_acc, out1, out4);
}

// Round 4
// 1050.256 us; speedup vs baseline: 1.9134x; 1.9134x over previous
//
#include <hip/hip_runtime.h>

#define N_TOK 32768
#define N_EMB 4096
#define DIM 256

typedef short bf16x8 __attribute__((ext_vector_type(8)));
typedef float f32x4 __attribute__((ext_vector_type(4)));
typedef unsigned short us8 __attribute__((ext_vector_type(8)));

// ---------------- ws layout ----------------
// [0, 16384)        counts    uint[4096]
// [16384, 16388)    loss_acc  float
// [16896, 33280)    e2_np     float[4096]
// [33280, 164352)   x2_np     float[32768]
// Big scratch (bf16 split, MFMA-fragment-shuffled) lives in the encodings
// output region (536 MB), overwritten by k_onehot afterwards.

static __device__ __forceinline__ unsigned short f2bf(float f) {
    unsigned int u = __float_as_uint(f);
    u = (u + 0x7fffu + ((u >> 16) & 1u)) >> 16;   // RTN-even
    return (unsigned short)u;
}
static __device__ __forceinline__ float bf2f(unsigned short h) {
    return __uint_as_float(((unsigned int)h) << 16);
}

// ---------------- numpy-pairwise fp32 row norms (r3-proven bit-exact) ------
__device__ __forceinline__ float pw128_sq(const float4* a4) {
#pragma clang fp contract(off)
    float4 v0 = a4[0], v1 = a4[1];
    float r0 = v0.x * v0.x, r1 = v0.y * v0.y, r2 = v0.z * v0.z, r3 = v0.w * v0.w;
    float r4 = v1.x * v1.x, r5 = v1.y * v1.y, r6 = v1.z * v1.z, r7 = v1.w * v1.w;
    #pragma unroll
    for (int i = 1; i < 16; ++i) {
        v0 = a4[2 * i]; v1 = a4[2 * i + 1];
        float s;
        s = v0.x * v0.x; r0 += s;
        s = v0.y * v0.y; r1 += s;
        s = v0.z * v0.z; r2 += s;
        s = v0.w * v0.w; r3 += s;
        s = v1.x * v1.x; r4 += s;
        s = v1.y * v1.y; r5 += s;
        s = v1.z * v1.z; r6 += s;
        s = v1.w * v1.w; r7 += s;
    }
    return ((r0 + r1) + (r2 + r3)) + ((r4 + r5) + (r6 + r7));
}

__global__ __launch_bounds__(256) void k_norm_np(const float* __restrict__ src,
                                                 float* __restrict__ dst, int nrows) {
#pragma clang fp contract(off)
    int row = blockIdx.x * 256 + threadIdx.x;
    if (row >= nrows) return;
    const float4* a = (const float4*)(src + (size_t)row * DIM);
    float lo = pw128_sq(a);
    float hi = pw128_sq(a + 32);
    dst[row] = lo + hi;
}

// ---------------- bf16 split + MFMA-fragment shuffle ----------------
// Output granule g = 1KB block (tile T of 16 rows, k-chunk C of 32):
// lane l's 16B = row T*16+(l&15), k = C*32 + (l>>4)*8 .. +8.
__global__ __launch_bounds__(256) void k_shuf(const float* __restrict__ src,
                                              unsigned short* __restrict__ hi,
                                              unsigned short* __restrict__ lo) {
    int tid = blockIdx.x * 256 + threadIdx.x;
    int b = tid >> 6, lane = tid & 63;
    int T = b >> 3, C = b & 7;
    int row = T * 16 + (lane & 15);
    int col = C * 32 + (lane >> 4) * 8;
    const float* s = src + (size_t)row * DIM + col;
    us8 h, l;
    #pragma unroll
    for (int j = 0; j < 8; ++j) {
        float v = s[j];
        unsigned short hb = f2bf(v);
        h[j] = hb;
        l[j] = f2bf(v - bf2f(hb));
    }
    *(us8*)(hi + (size_t)tid * 8) = h;
    *(us8*)(lo + (size_t)tid * 8) = l;
}

// ---------------- MFMA scoring + top-3 + np-exact refinement ----------------
// Block: 32 tokens x all codes (jt steps of 256). 4 waves, wave = M32 x N64.
// A (hi+lo) staged once in LDS via global_load_lds (fragment order = linear).
// B fragments register-direct from L2-resident shuffled W.
__global__ __launch_bounds__(256, 2) void k_score_mfma(
        const float* __restrict__ x, const float* __restrict__ w,
        const float* __restrict__ e2_np, const float* __restrict__ x2_np,
        const unsigned short* __restrict__ Xh, const unsigned short* __restrict__ Xl,
        const unsigned short* __restrict__ Wh, const unsigned short* __restrict__ Wl,
        float* __restrict__ out_idx, unsigned int* __restrict__ counts) {
    __shared__ __align__(16) short Abuf[16384];   // [hl][tile][C][lane][8] = 32 KB
    __shared__ __align__(16) float Sc[32 * 256];  // XOR-swizzled scores, 32 KB

    const int t = threadIdx.x;
    const int wave = t >> 6, lane = t & 63;
    const int tok0 = blockIdx.x * 32;
    const int tkn = t & 31, seg = t >> 5;   // reduction mapping: 8 threads/token

    // ---- stage A hi/lo (2 tiles x 8 chunks x 1KB x 2) ----
    #pragma unroll
    for (int i = 0; i < 8; ++i) {
        int idx = wave * 8 + i;             // 0..31
        int hl = idx >> 4, tile = (idx >> 3) & 1, C = idx & 7;
        int Tg = blockIdx.x * 2 + tile;
        const unsigned short* src =
            (hl ? Xl : Xh) + ((size_t)(Tg * 8 + C) * 64 + lane) * 8;
        __builtin_amdgcn_global_load_lds(
            (const __attribute__((address_space(1))) unsigned int*)src,
            (__attribute__((address_space(3))) unsigned int*)(Abuf + idx * 512),
            16, 0, 0);
    }
    __syncthreads();

    float d0 = -3.4e38f, d1 = -3.4e38f, d2 = -3.4e38f;
    int   i0 = 0, i1 = 0, i2 = 0;
    const int q = lane >> 4, c = lane & 15;

    for (int jt = 0; jt < N_EMB; jt += 256) {
        const int U0 = (jt >> 4) + wave * 4;   // my 4 code-tiles
        f32x4 acc[2][4] = {};
        #pragma unroll
        for (int C = 0; C < 8; ++C) {
            bf16x8 ah[2], al[2], bh[4], bl[4];
            #pragma unroll
            for (int m = 0; m < 2; ++m) {
                ah[m] = *(const bf16x8*)(Abuf + (size_t)((m)*8 + C) * 512 + lane * 8);
                al[m] = *(const bf16x8*)(Abuf + (size_t)((2 + m) * 8 + C) * 512 + lane * 8);
            }
            #pragma unroll
            for (int n = 0; n < 4; ++n) {
                size_t boff = (((size_t)(U0 + n) * 8 + C) * 64 + lane) * 8;
                bh[n] = *(const bf16x8*)(Wh + boff);
                bl[n] = *(const bf16x8*)(Wl + boff);
            }
            #pragma unroll
            for (int m = 0; m < 2; ++m)
                #pragma unroll
                for (int n = 0; n < 4; ++n) {
                    acc[m][n] = __builtin_amdgcn_mfma_f32_16x16x32_bf16(ah[m], bh[n], acc[m][n], 0, 0, 0);
                    acc[m][n] = __builtin_amdgcn_mfma_f32_16x16x32_bf16(ah[m], bl[n], acc[m][n], 0, 0, 0);
                    acc[m][n] = __builtin_amdgcn_mfma_f32_16x16x32_bf16(al[m], bh[n], acc[m][n], 0, 0, 0);
                }
        }
        __syncthreads();   // previous top-3 readers done
        // C/D layout: token row = m*16 + q*4 + r, code col = n*16 + c.
        // Swizzle: store col' = col ^ row (row<32) -> 2-way read aliasing (free).
        #pragma unroll
        for (int m = 0; m < 2; ++m) {
            int row = m * 16 + q * 4;
            #pragma unroll
            for (int n = 0; n < 4; ++n) {
                int col = wave * 64 + n * 16 + c;
                #pragma unroll
                for (int r = 0; r < 4; ++r)
                    Sc[(row + r) * 256 + (col ^ (row + r))] = acc[m][n][r];
            }
        }
        __syncthreads();
        // top-3 max-dot per (token, 32-code segment)
        int rb = tkn * 256 + seg * 32;
        int cbase = jt + seg * 32;
        #pragma unroll 8
        for (int i = 0; i < 32; ++i) {
            float d = Sc[rb + (i ^ tkn)];
            if (d > d2) {
                int code = cbase + i;
                if (d > d0)      { d2 = d1; i2 = i1; d1 = d0; i1 = i0; d0 = d; i0 = code; }
                else if (d > d1) { d2 = d1; i2 = i1; d1 = d;  i1 = code; }
                else             { d2 = d;  i2 = code; }
            }
        }
    }

    // ---- per-token best approx dot ----
    float* Red_d = Sc;                 // reuse (Sc dead now)
    int*   Red_i = (int*)(Sc + 256);
    __syncthreads();
    Red_d[tkn * 8 + seg] = d0;
    __syncthreads();
    float bv = -3.4e38f;
    #pragma unroll
    for (int k = 0; k < 8; ++k) bv = fmaxf(bv, Red_d[tkn * 8 + k]);

    // ---- np-fp32-exact refinement (r3-proven) ----
    float bd = 3.4e38f;
    int bi = 0x7fffffff;
    float x2 = x2_np[tok0 + tkn];
    const float4* xr = (const float4*)(x + (size_t)(tok0 + tkn) * DIM);
    float dv[3] = {d0, d1, d2};
    int   iv[3] = {i0, i1, i2};
    for (int cn = 0; cn < 3; ++cn) {
        if (dv[cn] >= bv - 6e-5f) {
            int code = iv[cn];
            const float4* wr = (const float4*)(w + (size_t)code * DIM);
            double dot = 0.0;
            for (int g = 0; g < 64; ++g) {
                float4 xv = xr[g];
                float4 wv = wr[g];
                dot += (double)xv.x * (double)wv.x;
                dot += (double)xv.y * (double)wv.y;
                dot += (double)xv.z * (double)wv.z;
                dot += (double)xv.w * (double)wv.w;
            }
            {
#pragma clang fp contract(off)
                float M  = (float)dot;
                float S  = x2 + e2_np[code];
                float dd = S - 2.0f * M;
                if (dd < bd || (dd == bd && code < bi)) { bd = dd; bi = code; }
            }
        }
    }
    __syncthreads();
    Red_d[tkn * 8 + seg] = bd;
    Red_i[tkn * 8 + seg] = bi;
    __syncthreads();
    if (t < 32) {
        float fv = Red_d[t * 8];
        int   fi = Red_i[t * 8];
        #pragma unroll
        for (int k = 1; k < 8; ++k) {
            float v = Red_d[t * 8 + k];
            int  ii = Red_i[t * 8 + k];
            if (v < fv || (v == fv && ii < fi)) { fv = v; fi = ii; }
        }
        out_idx[tok0 + t] = (float)fi;
        atomicAdd(&counts[fi], 1u);
    }
}

// ---------------- gather quantized + loss ----------------
__global__ __launch_bounds__(256) void k_gather(const float* __restrict__ x,
                                                const float* __restrict__ w,
                                                const float* __restrict__ out_idx,
                                                float* __restrict__ outq,
                                                float* __restrict__ loss_acc) {
    int gid = blockIdx.x * 256 + threadIdx.x;
    int token = gid >> 6;
    int d4 = gid & 63;
    int idx = (int)out_idx[token];
    float4 q  = ((const float4*)(w + (size_t)idx * DIM))[d4];
    float4 xv = ((const float4*)x)[gid];
    ((float4*)outq)[gid] = q;
    float dx = q.x - xv.x, dy = q.y - xv.y, dz = q.z - xv.z, dw = q.w - xv.w;
    float sse = dx * dx + dy * dy + dz * dz + dw * dw;
    #pragma unroll
    for (int off = 32; off > 0; off >>= 1) sse += __shfl_down(sse, off, 64);
    __shared__ float sred[4];
    int lane = threadIdx.x & 63, wv = threadIdx.x >> 6;
    if (lane == 0) sred[wv] = sse;
    __syncthreads();
    if (threadIdx.x == 0)
        atomicAdd(loss_acc, sred[0] + sred[1] + sred[2] + sred[3]);
}

// ---------------- one-hot encodings ----------------
__global__ __launch_bounds__(256) void k_onehot(const float* __restrict__ out_idx,
                                                float* __restrict__ enc) {
    int token = blockIdx.x;
    int idx = (int)out_idx[token];
    float4* row = (float4*)(enc + (size_t)token * N_EMB);
    #pragma unroll
    for (int p = 0; p < 4; ++p) {
        int g = threadIdx.x + 256 * p;
        float4 v = make_float4(0.f, 0.f, 0.f, 0.f);
        int d0 = g * 4;
        if (idx >= d0 && idx < d0 + 4) ((float*)&v)[idx - d0] = 1.0f;
        row[g] = v;
    }
}

// ---------------- perplexity + loss finalize ----------------
__global__ __launch_bounds__(256) void k_final(const unsigned int* __restrict__ counts,
                                               const float* __restrict__ loss_acc,
                                               float* __restrict__ out_perp,
                                               float* __restrict__ out_loss) {
    __shared__ float sred[4];
    int t = threadIdx.x;
    float h = 0.f;
    for (int k = t; k < N_EMB; k += 256) {
        float p = (float)counts[k] * (1.0f / N_TOK);
        h += p * logf(p + 1e-10f);
    }
    #pragma unroll
    for (int off = 32; off > 0; off >>= 1) h += __shfl_down(h, off, 64);
    if ((t & 63) == 0) sred[t >> 6] = h;
    __syncthreads();
    if (t == 0) {
        float s = sred[0] + sred[1] + sred[2] + sred[3];
        *out_perp = expf(-s);
        *out_loss = loss_acc[0] * 1.25f / 8388608.0f;
    }
}

extern "C" void kernel_launch(void* const* d_in, const int* in_sizes, int n_in,
                              void* d_out, int out_size, void* d_ws, size_t ws_size,
                              hipStream_t stream) {
    const float* x = (const float*)d_in[0];
    const float* w = (const float*)d_in[1];
    float* out  = (float*)d_out;
    float* out0 = out;                       // quantized_st [32768*256]
    float* out1 = out0 + 8388608;            // perplexity   [1]
    float* out2 = out1 + 1;                  // encodings    [32768*4096]
    float* out3 = out2 + 134217728;          // indices      [32768] (as float)
    float* out4 = out3 + 32768;              // loss         [1]

    unsigned int* counts = (unsigned int*)d_ws;
    float* loss_acc = (float*)((char*)d_ws + 16384);
    float* e2_np    = (float*)((char*)d_ws + 16896);
    float* x2_np    = (float*)((char*)d_ws + 33280);

    // bf16-split shuffled scratch inside the encodings region (36 MB of 536 MB);
    // k_onehot overwrites it after k_score_mfma has consumed it.
    unsigned short* Xh = (unsigned short*)out2;
    unsigned short* Xl = Xh + 8388608;
    unsigned short* Wh = Xl + 8388608;
    unsigned short* Wl = Wh + 1048576;

    hipMemsetAsync(d_ws, 0, 16640, stream);
    k_norm_np<<<N_EMB / 256, 256, 0, stream>>>(w, e2_np, N_EMB);
    k_norm_np<<<N_TOK / 256, 256, 0, stream>>>(x, x2_np, N_TOK);
    k_shuf<<<N_TOK * DIM / 8 / 256, 256, 0, stream>>>(x, Xh, Xl);
    k_shuf<<<N_EMB * DIM / 8 / 256, 256, 0, stream>>>(w, Wh, Wl);
    k_score_mfma<<<N_TOK / 32, 256, 0, stream>>>(x, w, e2_np, x2_np,
                                                 Xh, Xl, Wh, Wl, out3, counts);
    k_gather<<<N_TOK * 64 / 256, 256, 0, stream>>>(x, w, out3, out0, loss_acc);
    k_onehot<<<N_TOK, 256, 0, stream>>>(out3, out2);
    k_final<<<1, 256, 0, stream>>>(counts, loss_acc, out1, out4);
}

// Round 6
// 982.804 us; speedup vs baseline: 2.0447x; 1.0686x over previous
//
#include <hip/hip_runtime.h>

#define N_TOK 32768
#define N_EMB 4096
#define DIM 256

typedef short bf16x8 __attribute__((ext_vector_type(8)));
typedef float f32x4 __attribute__((ext_vector_type(4)));
typedef unsigned short us8 __attribute__((ext_vector_type(8)));

// ---------------- ws layout ----------------
// [0, 16384)        counts    uint[4096]
// [16384, 16388)    loss_acc  float
// [16896, 33280)    e2_np     float[4096]
// [33280, 164352)   x2_np     float[32768]
// Big scratch (bf16, MFMA-fragment-shuffled) lives 256B-aligned inside the
// encodings output region (536 MB), overwritten by k_onehot afterwards.

static __device__ __forceinline__ unsigned short f2bf(float f) {
    unsigned int u = __float_as_uint(f);
    u = (u + 0x7fffu + ((u >> 16) & 1u)) >> 16;   // RTN-even
    return (unsigned short)u;
}
static __device__ __forceinline__ float bf2f(unsigned short h) {
    return __uint_as_float(((unsigned int)h) << 16);
}

// ---------------- numpy-pairwise fp32 row norms (r3-proven bit-exact) ------
__device__ __forceinline__ float pw128_sq(const float4* a4) {
#pragma clang fp contract(off)
    float4 v0 = a4[0], v1 = a4[1];
    float r0 = v0.x * v0.x, r1 = v0.y * v0.y, r2 = v0.z * v0.z, r3 = v0.w * v0.w;
    float r4 = v1.x * v1.x, r5 = v1.y * v1.y, r6 = v1.z * v1.z, r7 = v1.w * v1.w;
    #pragma unroll
    for (int i = 1; i < 16; ++i) {
        v0 = a4[2 * i]; v1 = a4[2 * i + 1];
        float s;
        s = v0.x * v0.x; r0 += s;
        s = v0.y * v0.y; r1 += s;
        s = v0.z * v0.z; r2 += s;
        s = v0.w * v0.w; r3 += s;
        s = v1.x * v1.x; r4 += s;
        s = v1.y * v1.y; r5 += s;
        s = v1.z * v1.z; r6 += s;
        s = v1.w * v1.w; r7 += s;
    }
    return ((r0 + r1) + (r2 + r3)) + ((r4 + r5) + (r6 + r7));
}

__global__ __launch_bounds__(256) void k_norm_np(const float* __restrict__ src,
                                                 float* __restrict__ dst, int nrows) {
#pragma clang fp contract(off)
    int row = blockIdx.x * 256 + threadIdx.x;
    if (row >= nrows) return;
    const float4* a = (const float4*)(src + (size_t)row * DIM);
    float lo = pw128_sq(a);
    float hi = pw128_sq(a + 32);
    dst[row] = lo + hi;
}

// ---------------- bf16 split + MFMA-fragment shuffle ----------------
// Granule = 1KB (tile T of 16 rows, k-chunk C of 32):
// lane l's 16B = row T*16+(l&15), k = C*32 + (l>>4)*8 .. +8.
__global__ __launch_bounds__(256) void k_shuf2(const float* __restrict__ src,
                                               unsigned short* __restrict__ hi,
                                               unsigned short* __restrict__ lo) {
    int tid = blockIdx.x * 256 + threadIdx.x;
    int b = tid >> 6, lane = tid & 63;
    int T = b >> 3, C = b & 7;
    int row = T * 16 + (lane & 15);
    int col = C * 32 + (lane >> 4) * 8;
    const float* s = src + (size_t)row * DIM + col;
    us8 h, l;
    #pragma unroll
    for (int j = 0; j < 8; ++j) {
        float v = s[j];
        unsigned short hb = f2bf(v);
        h[j] = hb;
        l[j] = f2bf(v - bf2f(hb));
    }
    *(us8*)(hi + (size_t)tid * 8) = h;
    *(us8*)(lo + (size_t)tid * 8) = l;
}

__global__ __launch_bounds__(256) void k_shuf1(const float* __restrict__ src,
                                               unsigned short* __restrict__ hi) {
    int tid = blockIdx.x * 256 + threadIdx.x;
    int b = tid >> 6, lane = tid & 63;
    int T = b >> 3, C = b & 7;
    int row = T * 16 + (lane & 15);
    int col = C * 32 + (lane >> 4) * 8;
    const float* s = src + (size_t)row * DIM + col;
    us8 h;
    #pragma unroll
    for (int j = 0; j < 8; ++j) h[j] = f2bf(s[j]);
    *(us8*)(hi + (size_t)tid * 8) = h;
}

// ---------------- MFMA scoring + top-3 + np-exact refinement ----------------
// r4-proven skeleton. Block: 32 tokens x all codes (jt steps of 256). 4 waves,
// wave = M32 x N64. A (x hi+lo) staged once in LDS via global_load_lds;
// B = bf16(w) ONLY (|w|<=2.44e-4 -> dot noise sigma ~2.4e-6 << 8e-5 margin),
// register-direct from L2-resident Wh (2 MB < 4 MiB/XCD).
__global__ __launch_bounds__(256, 2) void k_score_mfma(
        const float* __restrict__ x, const float* __restrict__ w,
        const float* __restrict__ e2_np, const float* __restrict__ x2_np,
        const unsigned short* __restrict__ Xh, const unsigned short* __restrict__ Xl,
        const unsigned short* __restrict__ Wh,
        float* __restrict__ out_idx, unsigned int* __restrict__ counts) {
    __shared__ __align__(16) short Abuf[16384];   // [hl][tile][C][lane][8] = 32 KB
    __shared__ __align__(16) float Sc[32 * 256];  // XOR-swizzled scores, 32 KB

    const int t = threadIdx.x;
    const int wave = t >> 6, lane = t & 63;
    const int tok0 = blockIdx.x * 32;
    const int tkn = t & 31, seg = t >> 5;   // reduction mapping: 8 threads/token

    // ---- stage A hi/lo (2 tiles x 8 chunks x 1KB x 2) ----
    #pragma unroll
    for (int i = 0; i < 8; ++i) {
        int idx = wave * 8 + i;             // 0..31
        int hl = idx >> 4, tile = (idx >> 3) & 1, C = idx & 7;
        int Tg = blockIdx.x * 2 + tile;
        const unsigned short* src =
            (hl ? Xl : Xh) + ((size_t)(Tg * 8 + C) * 64 + lane) * 8;
        __builtin_amdgcn_global_load_lds(
            (const __attribute__((address_space(1))) unsigned int*)src,
            (__attribute__((address_space(3))) unsigned int*)(Abuf + idx * 512),
            16, 0, 0);
    }
    __syncthreads();

    float d0 = -3.4e38f, d1 = -3.4e38f, d2 = -3.4e38f;
    int   i0 = 0, i1 = 0, i2 = 0;
    const int q = lane >> 4, c = lane & 15;

    for (int jt = 0; jt < N_EMB; jt += 256) {
        const int U0 = (jt >> 4) + wave * 4;   // my 4 code-tiles
        f32x4 acc[2][4] = {};
        #pragma unroll
        for (int C = 0; C < 8; ++C) {
            bf16x8 ah[2], al[2], bh[4];
            #pragma unroll
            for (int m = 0; m < 2; ++m) {
                ah[m] = *(const bf16x8*)(Abuf + (size_t)((m)*8 + C) * 512 + lane * 8);
                al[m] = *(const bf16x8*)(Abuf + (size_t)((2 + m) * 8 + C) * 512 + lane * 8);
            }
            #pragma unroll
            for (int n = 0; n < 4; ++n) {
                size_t boff = (((size_t)(U0 + n) * 8 + C) * 64 + lane) * 8;
                bh[n] = *(const bf16x8*)(Wh + boff);
            }
            #pragma unroll
            for (int m = 0; m < 2; ++m)
                #pragma unroll
                for (int n = 0; n < 4; ++n) {
                    acc[m][n] = __builtin_amdgcn_mfma_f32_16x16x32_bf16(ah[m], bh[n], acc[m][n], 0, 0, 0);
                    acc[m][n] = __builtin_amdgcn_mfma_f32_16x16x32_bf16(al[m], bh[n], acc[m][n], 0, 0, 0);
                }
        }
        __syncthreads();   // previous top-3 readers done
        // C/D layout: token row = m*16 + q*4 + r, code col = n*16 + c.
        // Swizzle: store col' = col ^ row (row<32) -> 2-way read aliasing (free).
        #pragma unroll
        for (int m = 0; m < 2; ++m) {
            int row = m * 16 + q * 4;
            #pragma unroll
            for (int n = 0; n < 4; ++n) {
                int col = wave * 64 + n * 16 + c;
                #pragma unroll
                for (int r = 0; r < 4; ++r)
                    Sc[(row + r) * 256 + (col ^ (row + r))] = acc[m][n][r];
            }
        }
        __syncthreads();
        // top-3 max-dot per (token, 32-code segment)
        int rb = tkn * 256 + seg * 32;
        int cbase = jt + seg * 32;
        #pragma unroll 8
        for (int i = 0; i < 32; ++i) {
            float d = Sc[rb + (i ^ tkn)];
            if (d > d2) {
                int code = cbase + i;
                if (d > d0)      { d2 = d1; i2 = i1; d1 = d0; i1 = i0; d0 = d; i0 = code; }
                else if (d > d1) { d2 = d1; i2 = i1; d1 = d;  i1 = code; }
                else             { d2 = d;  i2 = code; }
            }
        }
    }

    // ---- per-token best approx dot ----
    float* Red_d = Sc;                 // reuse (Sc dead now)
    int*   Red_i = (int*)(Sc + 256);
    __syncthreads();
    Red_d[tkn * 8 + seg] = d0;
    __syncthreads();
    float bv = -3.4e38f;
    #pragma unroll
    for (int k = 0; k < 8; ++k) bv = fmaxf(bv, Red_d[tkn * 8 + k]);

    // ---- np-fp32-exact refinement (r3-proven) ----
    float bd = 3.4e38f;
    int bi = 0x7fffffff;
    float x2 = x2_np[tok0 + tkn];
    const float4* xr = (const float4*)(x + (size_t)(tok0 + tkn) * DIM);
    float dv[3] = {d0, d1, d2};
    int   iv[3] = {i0, i1, i2};
    for (int cn = 0; cn < 3; ++cn) {
        if (dv[cn] >= bv - 8e-5f) {
            int code = iv[cn];
            const float4* wr = (const float4*)(w + (size_t)code * DIM);
            double dot = 0.0;
            for (int g = 0; g < 64; ++g) {
                float4 xv = xr[g];
                float4 wv = wr[g];
                dot += (double)xv.x * (double)wv.x;
                dot += (double)xv.y * (double)wv.y;
                dot += (double)xv.z * (double)wv.z;
                dot += (double)xv.w * (double)wv.w;
            }
            {
#pragma clang fp contract(off)
                float M  = (float)dot;          // BLAS sgemm entry (~2e-9)
                float S  = x2 + e2_np[code];    // np broadcast add (fp32)
                float dd = S - 2.0f * M;        // fp32 sub -> ulp(~300) bucket
                if (dd < bd || (dd == bd && code < bi)) { bd = dd; bi = code; }
            }
        }
    }
    __syncthreads();
    Red_d[tkn * 8 + seg] = bd;
    Red_i[tkn * 8 + seg] = bi;
    __syncthreads();
    if (t < 32) {
        float fv = Red_d[t * 8];
        int   fi = Red_i[t * 8];
        #pragma unroll
        for (int k = 1; k < 8; ++k) {
            float v = Red_d[t * 8 + k];
            int  ii = Red_i[t * 8 + k];
            if (v < fv || (v == fv && ii < fi)) { fv = v; fi = ii; }
        }
        out_idx[tok0 + t] = (float)fi;
        atomicAdd(&counts[fi], 1u);
    }
}

// ---------------- gather quantized + loss ----------------
__global__ __launch_bounds__(256) void k_gather(const float* __restrict__ x,
                                                const float* __restrict__ w,
                                                const float* __restrict__ out_idx,
                                                float* __restrict__ outq,
                                                float* __restrict__ loss_acc) {
    int gid = blockIdx.x * 256 + threadIdx.x;
    int token = gid >> 6;
    int d4 = gid & 63;
    int idx = (int)out_idx[token];
    float4 q  = ((const float4*)(w + (size_t)idx * DIM))[d4];
    float4 xv = ((const float4*)x)[gid];
    ((float4*)outq)[gid] = q;
    float dx = q.x - xv.x, dy = q.y - xv.y, dz = q.z - xv.z, dw = q.w - xv.w;
    float sse = dx * dx + dy * dy + dz * dz + dw * dw;
    #pragma unroll
    for (int off = 32; off > 0; off >>= 1) sse += __shfl_down(sse, off, 64);
    __shared__ float sred[4];
    int lane = threadIdx.x & 63, wv = threadIdx.x >> 6;
    if (lane == 0) sred[wv] = sse;
    __syncthreads();
    if (threadIdx.x == 0)
        atomicAdd(loss_acc, sred[0] + sred[1] + sred[2] + sred[3]);
}

// ---------------- one-hot encodings ----------------
__global__ __launch_bounds__(256) void k_onehot(const float* __restrict__ out_idx,
                                                float* __restrict__ enc) {
    int token = blockIdx.x;
    int idx = (int)out_idx[token];
    float4* row = (float4*)(enc + (size_t)token * N_EMB);
    #pragma unroll
    for (int p = 0; p < 4; ++p) {
        int g = threadIdx.x + 256 * p;
        float4 v = make_float4(0.f, 0.f, 0.f, 0.f);
        int d0 = g * 4;
        if (idx >= d0 && idx < d0 + 4) ((float*)&v)[idx - d0] = 1.0f;
        row[g] = v;
    }
}

// ---------------- perplexity + loss finalize ----------------
__global__ __launch_bounds__(256) void k_final(const unsigned int* __restrict__ counts,
                                               const float* __restrict__ loss_acc,
                                               float* __restrict__ out_perp,
                                               float* __restrict__ out_loss) {
    __shared__ float sred[4];
    int t = threadIdx.x;
    float h = 0.f;
    for (int k = t; k < N_EMB; k += 256) {
        float p = (float)counts[k] * (1.0f / N_TOK);
        h += p * logf(p + 1e-10f);
    }
    #pragma unroll
    for (int off = 32; off > 0; off >>= 1) h += __shfl_down(h, off, 64);
    if ((t & 63) == 0) sred[t >> 6] = h;
    __syncthreads();
    if (t == 0) {
        float s = sred[0] + sred[1] + sred[2] + sred[3];
        *out_perp = expf(-s);
        *out_loss = loss_acc[0] * 1.25f / 8388608.0f;
    }
}

extern "C" void kernel_launch(void* const* d_in, const int* in_sizes, int n_in,
                              void* d_out, int out_size, void* d_ws, size_t ws_size,
                              hipStream_t stream) {
    const float* x = (const float*)d_in[0];
    const float* w = (const float*)d_in[1];
    float* out  = (float*)d_out;
    float* out0 = out;                       // quantized_st [32768*256]
    float* out1 = out0 + 8388608;            // perplexity   [1]
    float* out2 = out1 + 1;                  // encodings    [32768*4096]
    float* out3 = out2 + 134217728;          // indices      [32768] (as float)
    float* out4 = out3 + 32768;              // loss         [1]

    unsigned int* counts = (unsigned int*)d_ws;
    float* loss_acc = (float*)((char*)d_ws + 16384);
    float* e2_np    = (float*)((char*)d_ws + 16896);
    float* x2_np    = (float*)((char*)d_ws + 33280);

    // bf16 shuffled scratch inside the encodings region (34 MB of 536 MB),
    // 256B-aligned; k_onehot overwrites it after k_score_mfma consumed it.
    uintptr_t sb = ((uintptr_t)out2 + 255) & ~(uintptr_t)255;
    unsigned short* Xh = (unsigned short*)sb;     // 16 MB
    unsigned short* Xl = Xh + 8388608;            // 16 MB
    unsigned short* Wh = Xl + 8388608;            // 2 MB

    hipMemsetAsync(d_ws, 0, 16640, stream);
    k_norm_np<<<N_EMB / 256, 256, 0, stream>>>(w, e2_np, N_EMB);
    k_norm_np<<<N_TOK / 256, 256, 0, stream>>>(x, x2_np, N_TOK);
    k_shuf2<<<N_TOK * DIM / 8 / 256, 256, 0, stream>>>(x, Xh, Xl);
    k_shuf1<<<N_EMB * DIM / 8 / 256, 256, 0, stream>>>(w, Wh);
    k_score_mfma<<<N_TOK / 32, 256, 0, stream>>>(x, w, e2_np, x2_np,
                                                 Xh, Xl, Wh, out3, counts);
    k_gather<<<N_TOK * 64 / 256, 256, 0, stream>>>(x, w, out3, out0, loss_acc);
    k_onehot<<<N_TOK, 256, 0, stream>>>(out3, out2);
    k_final<<<1, 256, 0, stream>>>(counts, loss_acc, out1, out4);
}